// Round 8
// baseline (568.405 us; speedup 1.0000x reference)
//
#include <hip/hip_runtime.h>

// StyleLossW2 on MI355X. B=8, C=512, HW=16384. Output: 1 fp32 scalar.
// Round 7: fix r6 workspace overflow (NS arrays 136MiB > covP 128MiB spilled
// onto covdiag). Now: NS units 0..31 exactly fill covP; T3 reuses Ch/Cl
// (dead after G-GEMM); covdiag & scalars carved disjoint after G.
// Tuned 4-iteration NS (hat units), moments fused in G-GEMM epilogue,
// SYRK K-split 8, NT loads in convert. Hi/lo bf16 split arithmetic.

typedef unsigned short u16;
typedef __bf16 bf16_t;
typedef bf16_t bf16x8 __attribute__((ext_vector_type(8)));
typedef float f32x4 __attribute__((ext_vector_type(4)));

#define EPSV 1e-4f
#define MS 262144   // 512*512

// tuned NS coefficients (T_k = a*I - b*X_k), spectrum [0.2,1.4] -> 1+-2e-5
#define CA1 2.467890f
#define CB1 1.159097f
#define CA2 1.302300f
#define CB2 0.302300f
#define CA3 1.471101f
#define CB3 0.471096f
#define CA4 1.499154f
#define CB4 0.499153f
#define NUSAFE 1.35f

__device__ inline u16 f2b(float f) {
  bf16_t b = (bf16_t)f;
  return __builtin_bit_cast(u16, b);
}
__device__ inline float b2f(u16 u) {
  unsigned v = ((unsigned)u) << 16;
  return __builtin_bit_cast(float, v);
}

// ---------------- 2-phase double-buffered MFMA tile core --------------------
// (verified r2-r5: swizzled source + XOR'd ds_read -> 0 bank conflicts)
template <int FR, int LDA, int LDB, int SPS>
__device__ __forceinline__ void core2(const u16* A0, const u16* A1, const u16* A2,
                                      const u16* B0, const u16* B1, const u16* B2,
                                      int nsteps, u16* lds, f32x4 (&acc)[FR][FR],
                                      int wave, int lane) {
  const int TS = FR * 32 * 64;
  const u16* As[3] = {A0, A1, A2};
  const u16* Bs[3] = {B0, B1, B2};
  int rr = lane & 15, g4 = lane >> 4, wm = wave >> 1, wn = wave & 1;
  int swz = (rr & 7) << 3;
#pragma unroll
  for (int it = 0; it < FR; ++it) {
    int chunk = it * 4 + wave;
    __builtin_amdgcn_global_load_lds(
        (const __attribute__((address_space(1))) unsigned int*)(A0 + (size_t)(chunk * 8) * LDA),
        (__attribute__((address_space(3))) unsigned int*)&lds[chunk * 512], 16, 0, 0);
    __builtin_amdgcn_global_load_lds(
        (const __attribute__((address_space(1))) unsigned int*)(B0 + (size_t)(chunk * 8) * LDB),
        (__attribute__((address_space(3))) unsigned int*)&lds[TS + chunk * 512], 16, 0, 0);
  }
  __syncthreads();
  int buf = 0;
  for (int ks = 0; ks < nsteps; ++ks) {
    if (ks + 1 < nsteps) {
      int kn = ks + 1;
      int seg = kn / SPS;
      int k0 = (kn % SPS) * 64;
      const u16* A = As[seg];
      const u16* B = Bs[seg];
      u16* dst = lds + (buf ^ 1) * 2 * TS;
#pragma unroll
      for (int it = 0; it < FR; ++it) {
        int chunk = it * 4 + wave;
        __builtin_amdgcn_global_load_lds(
            (const __attribute__((address_space(1))) unsigned int*)(A + (size_t)(chunk * 8) * LDA + k0),
            (__attribute__((address_space(3))) unsigned int*)&dst[chunk * 512], 16, 0, 0);
        __builtin_amdgcn_global_load_lds(
            (const __attribute__((address_space(1))) unsigned int*)(B + (size_t)(chunk * 8) * LDB + k0),
            (__attribute__((address_space(3))) unsigned int*)&dst[TS + chunk * 512], 16, 0, 0);
      }
    }
    const u16* lb = lds + buf * 2 * TS;
#pragma unroll
    for (int kk = 0; kk < 2; ++kk) {
      int ko = (kk * 32 + g4 * 8) ^ swz;
      bf16x8 af[FR], bv[FR];
#pragma unroll
      for (int m = 0; m < FR; ++m)
        af[m] = *(const bf16x8*)&lb[(wm * FR * 16 + m * 16 + rr) * 64 + ko];
#pragma unroll
      for (int n = 0; n < FR; ++n)
        bv[n] = *(const bf16x8*)&lb[TS + (wn * FR * 16 + n * 16 + rr) * 64 + ko];
#pragma unroll
      for (int m = 0; m < FR; ++m)
#pragma unroll
        for (int n = 0; n < FR; ++n)
          acc[m][n] = __builtin_amdgcn_mfma_f32_16x16x32_bf16(af[m], bv[n],
                                                              acc[m][n], 0, 0, 0);
    }
    __syncthreads();
    buf ^= 1;
  }
}

// ---------------- convert fp32 -> bf16 (NT loads), per-row means ------------
__global__ __launch_bounds__(256) void k_convert(const float* __restrict__ X0,
                                                 const float* __restrict__ X1,
                                                 u16* __restrict__ Xh,
                                                 float* __restrict__ means) {
  int wave = threadIdx.x >> 6, lane = threadIdx.x & 63;
  int r = blockIdx.x * 4 + wave;
  const float* src = (r < 4096) ? X0 : X1;
  size_t off = (size_t)(r & 4095) * 16384;
  const f32x4* s4 = (const f32x4*)(src + off);
  uint4* dst = (uint4*)(Xh + (size_t)r * 16384);
  float sum = 0.0f;
#pragma unroll 8
  for (int i = 0; i < 32; ++i) {
    int c = i * 64 + lane;
    f32x4 a = __builtin_nontemporal_load(s4 + 2 * c);
    f32x4 b = __builtin_nontemporal_load(s4 + 2 * c + 1);
    sum += a.x + a.y + a.z + a.w + b.x + b.y + b.z + b.w;
    uint4 o;
    o.x = (unsigned)f2b(a.x) | ((unsigned)f2b(a.y) << 16);
    o.y = (unsigned)f2b(a.z) | ((unsigned)f2b(a.w) << 16);
    o.z = (unsigned)f2b(b.x) | ((unsigned)f2b(b.y) << 16);
    o.w = (unsigned)f2b(b.z) | ((unsigned)f2b(b.w) << 16);
    dst[c] = o;
  }
  for (int o = 32; o; o >>= 1) sum += __shfl_down(sum, o);
  if (lane == 0) means[r] = sum * (1.0f / 16384.0f);
}

// ---------------- SYRK: 1280 jobs = 16 mats x 10 sym-tiles x 8 K-eighths ----
__global__ __launch_bounds__(256) void k_syrk(const u16* __restrict__ Xh,
                                              float* __restrict__ covP) {
  const int TIv[10] = {0, 0, 0, 0, 1, 1, 1, 2, 2, 3};
  const int TJv[10] = {0, 1, 2, 3, 1, 2, 3, 2, 3, 3};
  int b = blockIdx.x;
  int sid = (b & 7) * 160 + (b >> 3);  // bijective XCD swizzle (1280 = 8*160)
  int mat = sid / 80, rem = sid % 80;
  int t = rem >> 3, q = rem & 7;
  int ti = TIv[t], tj = TJv[t];
  int tid = threadIdx.x, wave = tid >> 6, lane = tid & 63;
  __shared__ u16 lds[2 * 2 * 128 * 64];  // 64 KB
  f32x4 acc[4][4] = {};
  int srow = lane >> 3;
  int scol = ((lane & 7) * 8) ^ (srow << 3);
  const u16* base = Xh + (size_t)mat * 512 * 16384 + (size_t)q * 2048;
  const u16* Ab = base + (size_t)(ti * 128 + srow) * 16384 + scol;
  const u16* Bb = base + (size_t)(tj * 128 + srow) * 16384 + scol;
  core2<4, 16384, 16384, 64>(Ab, Ab, Ab, Bb, Bb, Bb, 32, lds, acc, wave, lane);
  int wm = wave >> 1, wn = wave & 1, rr = lane & 15, g4 = lane >> 4;
  float* out = covP + ((size_t)q * 16 + mat) * MS;
#pragma unroll
  for (int m = 0; m < 4; ++m)
#pragma unroll
    for (int n = 0; n < 4; ++n) {
      int rowb = ti * 128 + wm * 64 + m * 16 + g4 * 4;
      int col = tj * 128 + wn * 64 + n * 16 + rr;
      float v0 = acc[m][n][0], v1 = acc[m][n][1], v2 = acc[m][n][2], v3 = acc[m][n][3];
      out[(size_t)(rowb + 0) * 512 + col] = v0;
      out[(size_t)(rowb + 1) * 512 + col] = v1;
      out[(size_t)(rowb + 2) * 512 + col] = v2;
      out[(size_t)(rowb + 3) * 512 + col] = v3;
      if (ti != tj) {
        float4 tv = {v0, v1, v2, v3};
        *(float4*)&out[(size_t)col * 512 + rowb] = tv;
      }
    }
}

// ---- cov finish: sum 8 K-eighths, /HW - mean outer + eps I ->
//      hi/lo bf16 (C mats 0-7, TC mats 8-15) + fp32 diag; zero trP ----------
__global__ __launch_bounds__(256) void k_covfin2(const float* __restrict__ covP,
                                                 const float* __restrict__ means,
                                                 float* __restrict__ covdiag,
                                                 float* __restrict__ trP,
                                                 u16* __restrict__ Ch, u16* __restrict__ Cl,
                                                 u16* __restrict__ TCh, u16* __restrict__ TCl) {
  if (blockIdx.x == 0 && threadIdx.x < 16) trP[threadIdx.x] = 0.0f;
  const int NF4 = 16 * MS / 4;  // 1048576 float4s per K-eighth
  const float4* P = (const float4*)covP;
  for (int i4 = blockIdx.x * 256 + threadIdx.x; i4 < NF4; i4 += gridDim.x * 256) {
    float4 v0 = P[i4];
    float v[4] = {v0.x, v0.y, v0.z, v0.w};
#pragma unroll
    for (int k = 1; k < 8; ++k) {
      float4 a = P[(size_t)k * NF4 + i4];
      v[0] += a.x; v[1] += a.y; v[2] += a.z; v[3] += a.w;
    }
    int mat = i4 >> 16;
    int r = (i4 >> 7) & 511;
    int cb = (i4 & 127) * 4;
    float mr = means[mat * 512 + r];
    ushort4 h4, l4;
    unsigned short* ph = &h4.x;
    unsigned short* pl = &l4.x;
#pragma unroll
    for (int t = 0; t < 4; ++t) {
      float vv = v[t] * (1.0f / 16384.0f) - mr * means[mat * 512 + cb + t];
      if (r == cb + t) {
        vv += EPSV;
        covdiag[mat * 512 + r] = vv;
      }
      u16 hh = f2b(vv);
      ph[t] = hh;
      pl[t] = f2b(vv - b2f(hh));
    }
    int half = (mat >= 8);
    int loc4 = i4 - half * (NF4 / 2);
    ((ushort4*)(half ? TCh : Ch))[loc4] = h4;
    ((ushort4*)(half ? TCl : Cl))[loc4] = l4;
  }
}

// ---------------- generic NS GEMM -------------------------------------------
// v = c0[/nu]*acc + c1*(row==col) + cA*addF[r][c]; outputs any of
// {fp32, hi/lo bf16, transposed hi/lo}; optional moment atomics (G pass).
struct GJ {
  const u16 *Ah, *Al, *Bh, *Bl;   // B arrays are transposed-layout operands
  u16 *oH, *oL, *oTH, *oTL;
  float* oF;
  const float* addF;
  const float* trP;               // [16]: tr1[0..7], fro2[8..15] -> c0 /= nu
  float* tr1A; float* tr2A;       // atomic moment accumulation (G pass)
  float c0, c1, cA;
};

__global__ __launch_bounds__(256) void k_gg(GJ p, GJ q, int split) {
  int sid = ((blockIdx.x & 7) * (gridDim.x >> 3)) + (blockIdx.x >> 3);
  const GJ j = (sid < split) ? p : q;
  int blk = (sid < split) ? sid : sid - split;
  int mat = blk >> 6, tile = blk & 63;
  int ti = tile >> 3, tj = tile & 7;
  int tid = threadIdx.x, wave = tid >> 6, lane = tid & 63;
  __shared__ u16 lds[2 * 2 * 64 * 64];  // 32 KB
  f32x4 acc[2][2] = {};
  int srow = lane >> 3;
  int scol = ((lane & 7) * 8) ^ (srow << 3);
  size_t mo = (size_t)mat * MS;
  size_t ao = mo + (size_t)(ti * 64 + srow) * 512 + scol;
  size_t bo = mo + (size_t)(tj * 64 + srow) * 512 + scol;
  const u16* A0 = j.Ah + ao;
  const u16* A2 = j.Al + ao;
  const u16* B0 = j.Bh + bo;
  const u16* B1 = j.Bl + bo;
  core2<2, 512, 512, 8>(A0, A0, A2, B0, B1, B0, 24, lds, acc, wave, lane);
  int wm = wave >> 1, wn = wave & 1, rr = lane & 15, g4 = lane >> 4;
  float c0 = j.c0;
  if (j.trP) {  // c0 /= nu, nu = NUSAFE * ||G||_F^2 / tr(G)
    float t1 = j.trP[mat], t2 = j.trP[8 + mat];
    c0 *= t1 / (NUSAFE * t2);
  }
  float fro = 0.0f, dsum = 0.0f;
#pragma unroll
  for (int m = 0; m < 2; ++m)
#pragma unroll
    for (int n = 0; n < 2; ++n) {
      int rowb = ti * 64 + wm * 32 + m * 16 + g4 * 4;
      int col = tj * 64 + wn * 32 + n * 16 + rr;
      float v[4];
      ushort4 h4, l4;
      unsigned short* ph = &h4.x;
      unsigned short* pl = &l4.x;
#pragma unroll
      for (int v4 = 0; v4 < 4; ++v4) {
        float vv = c0 * acc[m][n][v4] + ((rowb + v4) == col ? j.c1 : 0.0f);
        if (j.addF) vv += j.cA * j.addF[mo + (size_t)(rowb + v4) * 512 + col];
        v[v4] = vv;
        u16 hh = f2b(vv);
        ph[v4] = hh;
        pl[v4] = f2b(vv - b2f(hh));
        if (j.tr2A) {
          fro += vv * vv;
          if ((rowb + v4) == col) dsum += vv;
        }
      }
      if (j.oF) {
#pragma unroll
        for (int v4 = 0; v4 < 4; ++v4)
          j.oF[mo + (size_t)(rowb + v4) * 512 + col] = v[v4];
      }
      if (j.oH) {
#pragma unroll
        for (int v4 = 0; v4 < 4; ++v4) {
          j.oH[mo + (size_t)(rowb + v4) * 512 + col] = ph[v4];
          j.oL[mo + (size_t)(rowb + v4) * 512 + col] = pl[v4];
        }
      }
      if (j.oTH) {
        *(ushort4*)&j.oTH[mo + (size_t)col * 512 + rowb] = h4;
        *(ushort4*)&j.oTL[mo + (size_t)col * 512 + rowb] = l4;
      }
    }
  if (j.tr2A) {
    for (int o = 32; o; o >>= 1) {
      fro += __shfl_down(fro, o);
      dsum += __shfl_down(dsum, o);
    }
    if (lane == 0) {
      atomicAdd(&j.tr2A[mat], fro);
      if (ti == tj) atomicAdd(&j.tr1A[mat], dsum);
    }
  }
}

// ---------------- T0 = a1*I - (b1/nu)*G, hi/lo + transpose ------------------
__global__ __launch_bounds__(256) void k_t0(const float* __restrict__ G,
                                            const float* __restrict__ trP,
                                            u16* __restrict__ Th, u16* __restrict__ Tl,
                                            u16* __restrict__ Tth, u16* __restrict__ Ttl) {
  __shared__ float lds[64][65];
  int b = blockIdx.x;  // 512 = 8 mats x 64 tiles
  int mat = b >> 6, tile = b & 63;
  int tr = tile >> 3, tc = tile & 7;
  float ib = CB1 * trP[mat] / (NUSAFE * trP[8 + mat]);  // b1/nu
  const float* src = G + (size_t)mat * MS + (size_t)(tr * 64) * 512 + tc * 64;
  size_t mo = (size_t)mat * MS;
  for (int i = threadIdx.x; i < 4096; i += 256) {
    int r = i >> 6, c = i & 63;
    float v = src[(size_t)r * 512 + c];
    lds[r][c] = v;
    int gr = tr * 64 + r, gc = tc * 64 + c;
    float tv = (gr == gc ? CA1 : 0.0f) - ib * v;
    size_t idx = mo + (size_t)gr * 512 + gc;
    u16 h = f2b(tv);
    Th[idx] = h; Tl[idx] = f2b(tv - b2f(h));
  }
  __syncthreads();
  for (int i = threadIdx.x; i < 4096; i += 256) {
    int r = i >> 6, c = i & 63;
    float v = lds[c][r];
    int gr = tc * 64 + r, gc = tr * 64 + c;
    float tv = (gr == gc ? CA1 : 0.0f) - ib * v;
    size_t idx = mo + (size_t)gr * 512 + gc;
    u16 h = f2b(tv);
    Tth[idx] = h; Ttl[idx] = f2b(tv - b2f(h));
  }
}

// ---------------- trace dot: sum (Y3T .* T3) per chunk ----------------------
__global__ __launch_bounds__(256) void k_dot(const u16* __restrict__ Yth,
                                             const u16* __restrict__ Ytl,
                                             const u16* __restrict__ Th,
                                             const u16* __restrict__ Tl,
                                             float* __restrict__ dotp) {
  int b = blockIdx.x;  // 64 = 8 mats x 8 chunks
  size_t off = (size_t)b * 32768;
  float s = 0.0f;
  for (int i = threadIdx.x; i < 8192; i += 256) {
    ushort4 yh = ((const ushort4*)(Yth + off))[i];
    ushort4 yl = ((const ushort4*)(Ytl + off))[i];
    ushort4 th = ((const ushort4*)(Th + off))[i];
    ushort4 tl = ((const ushort4*)(Tl + off))[i];
    s += (b2f(yh.x) + b2f(yl.x)) * (b2f(th.x) + b2f(tl.x));
    s += (b2f(yh.y) + b2f(yl.y)) * (b2f(th.y) + b2f(tl.y));
    s += (b2f(yh.z) + b2f(yl.z)) * (b2f(th.z) + b2f(tl.z));
    s += (b2f(yh.w) + b2f(yl.w)) * (b2f(th.w) + b2f(tl.w));
  }
  for (int o = 32; o; o >>= 1) s += __shfl_down(s, o);
  __shared__ float red[4];
  if ((threadIdx.x & 63) == 0) red[threadIdx.x >> 6] = s;
  __syncthreads();
  if (threadIdx.x == 0) dotp[b] = red[0] + red[1] + red[2] + red[3];
}

// ---------------- final scalar ----------------------------------------------
// loss = mean_diff + (sum covdiag - sum_m 2*dot_hat_m/sqrt(nu_m)) / 4096
__global__ __launch_bounds__(256) void k_final(const float* __restrict__ dotp,
                                               const float* __restrict__ trP,
                                               const float* __restrict__ covdiag,
                                               const float* __restrict__ means,
                                               float* __restrict__ out) {
  float s = 0.0f;
  for (int i = threadIdx.x; i < 4096; i += 256) {
    float dm = means[i] - means[4096 + i];
    s += dm * dm;
  }
  for (int i = threadIdx.x; i < 8192; i += 256) s += covdiag[i];
  if (threadIdx.x < 8) {
    int m = threadIdx.x;
    float nu = NUSAFE * trP[8 + m] / trP[m];
    float tr = 0.0f;
#pragma unroll
    for (int i = 0; i < 8; ++i) tr += dotp[m * 8 + i];
    s -= 2.0f * tr / sqrtf(nu);
  }
  for (int o = 32; o; o >>= 1) s += __shfl_down(s, o);
  __shared__ float red[4];
  if ((threadIdx.x & 63) == 0) red[threadIdx.x >> 6] = s;
  __syncthreads();
  if (threadIdx.x == 0)
    out[0] = (red[0] + red[1] + red[2] + red[3]) * (1.0f / 4096.0f);
}

// ---------------- host ------------------------------------------------------
extern "C" void kernel_launch(void* const* d_in, const int* in_sizes, int n_in,
                              void* d_out, int out_size, void* d_ws, size_t ws_size,
                              hipStream_t stream) {
  (void)in_sizes; (void)n_in; (void)out_size; (void)ws_size;
  const float* X0 = (const float*)d_in[0];
  const float* X1 = (const float*)d_in[1];
  float* out = (float*)d_out;

  char* w = (char*)d_ws;
  auto carve = [&](size_t bytes) -> void* {
    void* r = (void*)w;
    w += (bytes + 255) & ~(size_t)255;
    return r;
  };
  u16*   Xh   = (u16*)carve(2ull * 8 * 512 * 16384 * 2);  // 256 MiB
  float* covP = (float*)carve(8ull * 16 * MS * 4);        // 128 MiB = 32 units
  u16* Ch  = (u16*)carve(8 * MS * 2); u16* Cl  = (u16*)carve(8 * MS * 2);
  u16* TCh = (u16*)carve(8 * MS * 2); u16* TCl = (u16*)carve(8 * MS * 2);
  float* G = (float*)carve(8ull * MS * 4);                // 8 MiB
  float* covdiag = (float*)carve(16 * 512 * 4);           // after G: no overlap
  float* means = (float*)carve(8192 * 4);
  float* trP   = (float*)carve(16 * 4);   // tr1[8], fro2[8]
  float* dotp  = (float*)carve(64 * 4);

  // NS bf16 arrays (4 MiB units) aliased into covP: EXACTLY 32 units (0..31).
  // covP is dead after k_covfin2; units written starting step 3.
  const size_t AS = 8 * MS;  // elements per unit (4 MiB)
  u16* U0 = (u16*)covP;
  auto unit = [&](int i) -> u16* { return U0 + (size_t)i * AS; };
  u16 *Gh = unit(0), *Gl = unit(1), *Gth = unit(2), *Gtl = unit(3);
  u16 *T0h = unit(4), *T0l = unit(5), *T0th = unit(6), *T0tl = unit(7);
  u16 *Y1h = unit(8), *Y1l = unit(9), *Y1th = unit(10), *Y1tl = unit(11);
  u16 *T1h = unit(12), *T1l = unit(13), *T1th = unit(14), *T1tl = unit(15);
  u16 *Y2h = unit(16), *Y2l = unit(17), *Y2th = unit(18), *Y2tl = unit(19);
  u16 *Z2h = unit(20), *Z2l = unit(21), *Z2th = unit(22), *Z2tl = unit(23);
  u16 *T2h = unit(24), *T2l = unit(25), *T2th = unit(26), *T2tl = unit(27);
  u16 *Y3th = unit(28), *Y3tl = unit(29);
  u16 *Z3h = unit(30), *Z3l = unit(31);
  u16 *T3h = Ch, *T3l = Cl;   // Ch/Cl dead after step 3 (G GEMM)

  // 1) fp32 -> bf16 + means
  k_convert<<<2048, 256, 0, stream>>>(X0, X1, Xh, means);

  // 2) SYRK (K-split 8) + fused finish/split (also zeroes trP)
  k_syrk<<<1280, 256, 0, stream>>>(Xh, covP);
  k_covfin2<<<2048, 256, 0, stream>>>(covP, means, covdiag, trP, Ch, Cl, TCh, TCl);

  // 3) G = C @ TC; epilogue: G fp32, Ghat hi/lo + transposes, moments
  {
    GJ gj = {Ch, Cl, TCh, TCl, Gh, Gl, Gth, Gtl, G,
             nullptr, nullptr, trP, trP + 8, 1.0f, 0.0f, 0.0f};
    k_gg<<<512, 256, 0, stream>>>(gj, gj, 512);
  }

  // 4) T0 = a1*I - (b1/nu)*G  (Z1 = T0)
  k_t0<<<512, 256, 0, stream>>>(G, trP, T0h, T0l, T0th, T0tl);

  // 5) Y1_hat = a1*G - (b1/nu)*G^2
  {
    GJ yj = {Gh, Gl, Gth, Gtl, Y1h, Y1l, Y1th, Y1tl, nullptr,
             G, trP, nullptr, nullptr, -CB1, 0.0f, CA1};
    k_gg<<<512, 256, 0, stream>>>(yj, yj, 512);
  }
  // 6) T1 = a2*I - (b2/nu) * Z1 @ Y1_hat
  {
    GJ tj = {T0h, T0l, Y1th, Y1tl, T1h, T1l, T1th, T1tl, nullptr,
             nullptr, trP, nullptr, nullptr, -CB2, CA2, 0.0f};
    k_gg<<<512, 256, 0, stream>>>(tj, tj, 512);
  }
  // 7) Y2 = Y1 @ T1 ; Z2 = T1 @ Z1
  {
    GJ yj = {Y1h, Y1l, T1th, T1tl, Y2h, Y2l, Y2th, Y2tl, nullptr,
             nullptr, nullptr, nullptr, nullptr, 1.0f, 0.0f, 0.0f};
    GJ zj = {T1h, T1l, T0th, T0tl, Z2h, Z2l, Z2th, Z2tl, nullptr,
             nullptr, nullptr, nullptr, nullptr, 1.0f, 0.0f, 0.0f};
    k_gg<<<1024, 256, 0, stream>>>(yj, zj, 512);
  }
  // 8) T2 = a3*I - (b3/nu) * Z2 @ Y2
  {
    GJ tj = {Z2h, Z2l, Y2th, Y2tl, T2h, T2l, T2th, T2tl, nullptr,
             nullptr, trP, nullptr, nullptr, -CB3, CA3, 0.0f};
    k_gg<<<512, 256, 0, stream>>>(tj, tj, 512);
  }
  // 9) Y3 = Y2 @ T2 (transposed out only); Z3 = T2 @ Z2 (normal only)
  {
    GJ yj = {Y2h, Y2l, T2th, T2tl, nullptr, nullptr, Y3th, Y3tl, nullptr,
             nullptr, nullptr, nullptr, nullptr, 1.0f, 0.0f, 0.0f};
    GJ zj = {T2h, T2l, Z2th, Z2tl, Z3h, Z3l, nullptr, nullptr, nullptr,
             nullptr, nullptr, nullptr, nullptr, 1.0f, 0.0f, 0.0f};
    k_gg<<<1024, 256, 0, stream>>>(yj, zj, 512);
  }
  // 10) T3 = a4*I - (b4/nu) * Z3 @ Y3  (into Ch/Cl, dead)
  {
    GJ tj = {Z3h, Z3l, Y3th, Y3tl, T3h, T3l, nullptr, nullptr, nullptr,
             nullptr, trP, nullptr, nullptr, -CB4, CA4, 0.0f};
    k_gg<<<512, 256, 0, stream>>>(tj, tj, 512);
  }

  // 11) trace = <Y3^T, T3> = tr(Y4_hat);  loss
  k_dot<<<64, 256, 0, stream>>>(Y3th, Y3tl, T3h, T3l, dotp);
  k_final<<<1, 256, 0, stream>>>(dotp, trP, covdiag, means, out);
}